// Round 2
// baseline (685.694 us; speedup 1.0000x reference)
//
#include <hip/hip_runtime.h>
#include <hip/hip_bf16.h>
#include <math.h>

#define F_IN 512
#define HID  16
#define C_OUT 40

#define BSH    7            // 128 nodes per coarse bucket
#define BNODES 128
#define MAXNB  1024         // N=100000 -> NB=782

#define EPB 8192            // edges per block in count/partition
#define CTH 512

__device__ __forceinline__ unsigned short f2bf(float f) {
    unsigned u = __float_as_uint(f);
    unsigned r = (u + 0x7FFF + ((u >> 16) & 1)) >> 16;   // RNE
    return (unsigned short)r;
}
__device__ __forceinline__ float bf2f(unsigned short h) {
    return __uint_as_float(((unsigned)h) << 16);
}

// ---------------------------------------------------------------------------
// K0: zero global bucket counters
// ---------------------------------------------------------------------------
__global__ __launch_bounds__(1024) void k_zero(int* __restrict__ g, int n) {
    int t = threadIdx.x;
    if (t < n) g[t] = 0;
}

// ---------------------------------------------------------------------------
// K1: coarse bucket histogram via LDS
// ---------------------------------------------------------------------------
__global__ __launch_bounds__(CTH) void k_count(const int* __restrict__ col,
                                               int* __restrict__ gcnt,
                                               int E, int NB) {
    __shared__ int lc[MAXNB];
    int t = threadIdx.x;
    for (int i = t; i < NB; i += CTH) lc[i] = 0;
    __syncthreads();
    int base = blockIdx.x * EPB;
#pragma unroll
    for (int i = 0; i < EPB / CTH; ++i) {
        int e = base + t + i * CTH;
        if (e < E) atomicAdd(&lc[col[e] >> BSH], 1);
    }
    __syncthreads();
    for (int i = t; i < NB; i += CTH)
        if (lc[i]) atomicAdd(&gcnt[i], lc[i]);
}

// ---------------------------------------------------------------------------
// K2: exclusive scan of bucket counts; also offs[N] = E sentinel
// ---------------------------------------------------------------------------
__global__ __launch_bounds__(1024) void k_scan(const int* __restrict__ gcnt,
                                               int* __restrict__ bo,
                                               int* __restrict__ bcur,
                                               int* __restrict__ offs,
                                               int NB, int N, int E) {
    __shared__ int s[1024];
    int t = threadIdx.x;
    int v = (t < NB) ? gcnt[t] : 0;
    s[t] = v;
    __syncthreads();
    for (int off = 1; off < 1024; off <<= 1) {
        int x = (t >= off) ? s[t - off] : 0;
        __syncthreads();
        s[t] += x;
        __syncthreads();
    }
    if (t < NB) { int o = s[t] - v; bo[t] = o; bcur[t] = o; }
    if (t == 0) { bo[NB] = E; offs[N] = E; }
}

// ---------------------------------------------------------------------------
// K3: partition edges into coarse buckets. record .x=(row<<7)|col_low, .y=ew
// ---------------------------------------------------------------------------
__global__ __launch_bounds__(CTH) void k_part(const int* __restrict__ row,
                                              const int* __restrict__ col,
                                              const float* __restrict__ ew,
                                              int* __restrict__ bcur,
                                              int2* __restrict__ st,
                                              int E, int NB) {
    __shared__ int lc[MAXNB];
    __shared__ int lb[MAXNB];
    int t = threadIdx.x;
    for (int i = t; i < NB; i += CTH) lc[i] = 0;
    __syncthreads();
    int base = blockIdx.x * EPB;
#pragma unroll
    for (int i = 0; i < EPB / CTH; ++i) {
        int e = base + t + i * CTH;
        if (e < E) atomicAdd(&lc[col[e] >> BSH], 1);
    }
    __syncthreads();
    for (int i = t; i < NB; i += CTH) {
        int c = lc[i];
        lb[i] = c ? atomicAdd(&bcur[i], c) : 0;
    }
    __syncthreads();
    for (int i = t; i < NB; i += CTH) lc[i] = 0;  // reuse as rank counter
    __syncthreads();
#pragma unroll
    for (int i = 0; i < EPB / CTH; ++i) {
        int e = base + t + i * CTH;
        if (e < E) {
            int c = col[e];
            int b = c >> BSH;
            int r = atomicAdd(&lc[b], 1);
            st[lb[b] + r] = make_int2((row[e] << BSH) | (c & (BNODES - 1)),
                                      __float_as_int(ew[e]));
        }
    }
}

// ---------------------------------------------------------------------------
// K4: per-bucket exact counting sort (two passes, no record buffer in LDS).
// ---------------------------------------------------------------------------
__global__ __launch_bounds__(256) void k_sort(const int* __restrict__ bo,
                                              const int2* __restrict__ st,
                                              int2* __restrict__ st2,
                                              int* __restrict__ offs,
                                              float* __restrict__ dinv, int N) {
    __shared__ int cnt[BNODES];
    __shared__ float wsum[BNODES];
    __shared__ int off[BNODES];
    int t = threadIdx.x;
    int b = blockIdx.x;
    if (t < BNODES) { cnt[t] = 0; wsum[t] = 0.0f; }
    __syncthreads();
    int beg = bo[b], end = bo[b + 1];
    // pass A: histogram + weighted degree
    for (int e = beg + t; e < end; e += 256) {
        int2 rec = st[e];
        int cl = rec.x & (BNODES - 1);
        atomicAdd(&cnt[cl], 1);
        atomicAdd(&wsum[cl], __int_as_float(rec.y));
    }
    __syncthreads();
    // scan cnt[128] (Hillis-Steele)
    if (t < BNODES) off[t] = cnt[t];
    __syncthreads();
    for (int o = 1; o < BNODES; o <<= 1) {
        int v = (t < BNODES && t >= o) ? off[t - o] : 0;
        __syncthreads();
        if (t < BNODES) off[t] += v;
        __syncthreads();
    }
    if (t < BNODES) {
        int ex = off[t] - cnt[t];       // exclusive
        off[t] = ex;
        int n = b * BNODES + t;
        if (n < N) {
            offs[n] = beg + ex;
            dinv[n] = rsqrtf(1.0f + wsum[t]);
        }
        cnt[t] = 0;                     // reuse as rank counter
    }
    __syncthreads();
    // pass B: place
    for (int e = beg + t; e < end; e += 256) {
        int2 rec = st[e];
        int cl = rec.x & (BNODES - 1);
        int r = atomicAdd(&cnt[cl], 1);
        st2[beg + off[cl] + r] = make_int2(rec.x >> BSH, rec.y);
    }
}

// ---------------------------------------------------------------------------
// K5: h1' = dinv * (x @ W1), stored bf16 (16 x bf16 = 32 B per node).
// Thread-per-node (round-0 structure: wave-uniform W -> scalar loads), but
// software-pipelined with two named 16 x float4 register batches so ~16
// independent global loads are in flight per thread. Grid is only 391
// blocks (~1.5 waves/SIMD), so VGPRs are free: __launch_bounds__(256,1).
// ---------------------------------------------------------------------------
__global__ __launch_bounds__(256, 1) void k_gemm1(const float* __restrict__ x,
                                                  const float* __restrict__ W,
                                                  const float* __restrict__ dinv,
                                                  unsigned short* __restrict__ hb,
                                                  int N) {
    int n = blockIdx.x * 256 + threadIdx.x;
    if (n >= N) return;
    float acc[HID];
#pragma unroll
    for (int j = 0; j < HID; ++j) acc[j] = 0.0f;
    const float4* xr = (const float4*)(x + (size_t)n * F_IN);

    float4 xa[16], xb[16];

#define LOADB(buf, kb)                                                      \
    {                                                                       \
        _Pragma("unroll")                                                   \
        for (int i = 0; i < 16; ++i) buf[i] = xr[(kb) * 16 + i];            \
    }
#define COMPB(buf, kb)                                                      \
    {                                                                       \
        _Pragma("unroll")                                                   \
        for (int i = 0; i < 16; ++i) {                                      \
            const float* wk = W + ((kb) * 16 + i) * 4 * HID; /* uniform */  \
            _Pragma("unroll")                                               \
            for (int j = 0; j < HID; ++j) acc[j] += buf[i].x * wk[j];       \
            _Pragma("unroll")                                               \
            for (int j = 0; j < HID; ++j) acc[j] += buf[i].y * wk[HID + j]; \
            _Pragma("unroll")                                               \
            for (int j = 0; j < HID; ++j) acc[j] += buf[i].z * wk[2 * HID + j]; \
            _Pragma("unroll")                                               \
            for (int j = 0; j < HID; ++j) acc[j] += buf[i].w * wk[3 * HID + j]; \
        }                                                                   \
    }

    LOADB(xa, 0);
    // 8 batches of 16 float4 (= 64 floats) each; unrolled by 2 so the two
    // buffers alternate with compile-time indices (no scratch spill).
    for (int kb = 0; kb < 8; kb += 2) {
        LOADB(xb, kb + 1);
        COMPB(xa, kb);
        if (kb + 2 < 8) LOADB(xa, kb + 2);
        COMPB(xb, kb + 1);
    }
#undef LOADB
#undef COMPB

    float d = dinv[n];
    unsigned pk[8];
#pragma unroll
    for (int j = 0; j < 8; ++j)
        pk[j] = (unsigned)f2bf(d * acc[2 * j]) |
                ((unsigned)f2bf(d * acc[2 * j + 1]) << 16);
    uint4* hp = (uint4*)(hb + (size_t)n * HID);
    hp[0] = make_uint4(pk[0], pk[1], pk[2], pk[3]);
    hp[1] = make_uint4(pk[4], pk[5], pk[6], pk[7]);
}

// ---------------------------------------------------------------------------
// K6: layer-1 aggregate. Wave per node; lane = 4*i+q (i edge slot, q dim quad).
// ---------------------------------------------------------------------------
__global__ __launch_bounds__(256) void k_agg1(const int* __restrict__ offs,
                                              const int2* __restrict__ st2,
                                              const float* __restrict__ dinv,
                                              const unsigned short* __restrict__ srcb,
                                              const float* __restrict__ bias,
                                              unsigned short* __restrict__ dstb,
                                              int N) {
    int t = threadIdx.x;
    int lane = t & 63, w = t >> 6;
    int n = blockIdx.x * 4 + w;
    if (n >= N) return;
    int q = lane & 3, i = lane >> 2;
    int beg = offs[n], end = offs[n + 1];
    float4 acc = make_float4(0.f, 0.f, 0.f, 0.f);
    for (int e = beg + i; e < end; e += 16) {
        int2 rec = st2[e];
        float wt = __int_as_float(rec.y);
        ushort4 v = ((const ushort4*)(srcb + (size_t)rec.x * HID))[q];
        acc.x += wt * bf2f(v.x);
        acc.y += wt * bf2f(v.y);
        acc.z += wt * bf2f(v.z);
        acc.w += wt * bf2f(v.w);
    }
#pragma unroll
    for (int off = 4; off < 64; off <<= 1) {
        acc.x += __shfl_xor(acc.x, off, 64);
        acc.y += __shfl_xor(acc.y, off, 64);
        acc.z += __shfl_xor(acc.z, off, 64);
        acc.w += __shfl_xor(acc.w, off, 64);
    }
    if (i == 0) {
        float d = dinv[n];
        ushort4 sv = ((const ushort4*)(srcb + (size_t)n * HID))[q];
        float4 bq = ((const float4*)bias)[q];
        float r0 = d * fmaxf(d * (acc.x + bf2f(sv.x)) + bq.x, 0.f);
        float r1 = d * fmaxf(d * (acc.y + bf2f(sv.y)) + bq.y, 0.f);
        float r2 = d * fmaxf(d * (acc.z + bf2f(sv.z)) + bq.z, 0.f);
        float r3 = d * fmaxf(d * (acc.w + bf2f(sv.w)) + bq.w, 0.f);
        ((ushort4*)(dstb + (size_t)n * HID))[q] =
            make_ushort4(f2bf(r0), f2bf(r1), f2bf(r2), f2bf(r3));
    }
}

// ---------------------------------------------------------------------------
// K7: layer-2 aggregate fused with W2 matvec + bias + log_softmax.
// ---------------------------------------------------------------------------
__global__ __launch_bounds__(256) void k_agg2(const int* __restrict__ offs,
                                              const int2* __restrict__ st2,
                                              const float* __restrict__ dinv,
                                              const unsigned short* __restrict__ srcb,
                                              const float* __restrict__ W2,
                                              const float* __restrict__ b2,
                                              float* __restrict__ out, int N) {
    __shared__ float Ws[HID * C_OUT];
    __shared__ float bs[C_OUT];
    int t = threadIdx.x;
    for (int iw = t; iw < HID * C_OUT; iw += 256) Ws[iw] = W2[iw];
    if (t < C_OUT) bs[t] = b2[t];
    __syncthreads();

    int lane = t & 63, w = t >> 6;
    int n = blockIdx.x * 4 + w;
    if (n >= N) return;
    int q = lane & 3, i = lane >> 2;
    int beg = offs[n], end = offs[n + 1];
    float4 acc = make_float4(0.f, 0.f, 0.f, 0.f);
    for (int e = beg + i; e < end; e += 16) {
        int2 rec = st2[e];
        float wt = __int_as_float(rec.y);
        ushort4 v = ((const ushort4*)(srcb + (size_t)rec.x * HID))[q];
        acc.x += wt * bf2f(v.x);
        acc.y += wt * bf2f(v.y);
        acc.z += wt * bf2f(v.z);
        acc.w += wt * bf2f(v.w);
    }
#pragma unroll
    for (int off = 4; off < 64; off <<= 1) {
        acc.x += __shfl_xor(acc.x, off, 64);
        acc.y += __shfl_xor(acc.y, off, 64);
        acc.z += __shfl_xor(acc.z, off, 64);
        acc.w += __shfl_xor(acc.w, off, 64);
    }
    // every lane now holds the full sum for its quad q
    float d = dinv[n];
    ushort4 sv = ((const ushort4*)(srcb + (size_t)n * HID))[q];
    float gq[4];
    gq[0] = d * (acc.x + bf2f(sv.x));
    gq[1] = d * (acc.y + bf2f(sv.y));
    gq[2] = d * (acc.z + bf2f(sv.z));
    gq[3] = d * (acc.w + bf2f(sv.w));
    // assemble all 16 dims in every lane (quads live in lanes base..base+3)
    float g16[16];
    int base = lane & ~3;
#pragma unroll
    for (int qq = 0; qq < 4; ++qq) {
#pragma unroll
        for (int k = 0; k < 4; ++k)
            g16[qq * 4 + k] = __shfl(gq[k], base + qq, 64);
    }
    float logit = -INFINITY;
    if (lane < C_OUT) {
        float a = bs[lane];
#pragma unroll
        for (int j = 0; j < HID; ++j) a += g16[j] * Ws[j * C_OUT + lane];
        logit = a;
    }
    float m = logit;
#pragma unroll
    for (int off = 32; off > 0; off >>= 1) m = fmaxf(m, __shfl_xor(m, off, 64));
    float ex = (lane < C_OUT) ? __expf(logit - m) : 0.0f;
    float s = ex;
#pragma unroll
    for (int off = 32; off > 0; off >>= 1) s += __shfl_xor(s, off, 64);
    if (lane < C_OUT) out[(size_t)n * C_OUT + lane] = logit - m - __logf(s);
}

// ---------------------------------------------------------------------------
extern "C" void kernel_launch(void* const* d_in, const int* in_sizes, int n_in,
                              void* d_out, int out_size, void* d_ws, size_t ws_size,
                              hipStream_t stream) {
    const float* x   = (const float*)d_in[0];
    const int*   ei  = (const int*)d_in[1];
    const float* ew  = (const float*)d_in[2];
    const float* W1  = (const float*)d_in[3];
    const float* b1  = (const float*)d_in[4];
    const float* W2  = (const float*)d_in[5];
    const float* b2  = (const float*)d_in[6];
    float* out = (float*)d_out;

    const int N = in_sizes[0] / F_IN;          // 100000
    const int E = in_sizes[2];                 // 3200000
    const int* row = ei;
    const int* col = ei + E;
    const int NB = (N + BNODES - 1) >> BSH;    // 782

    // workspace carve (4-byte words)
    int* wsi = (int*)d_ws;
    size_t o = 0;
    int* gcnt  = wsi + o; o += MAXNB;
    int* bo    = wsi + o; o += MAXNB + 1;
    int* bcur  = wsi + o; o += MAXNB;
    int* offs  = wsi + o; o += (size_t)N + 8;
    float* dinv = (float*)(wsi + o); o += N;
    unsigned short* h1b = (unsigned short*)(wsi + o); o += (size_t)N * HID / 2;
    unsigned short* a1b = (unsigned short*)(wsi + o); o += (size_t)N * HID / 2;
    int2* st   = (int2*)(wsi + o); o += (size_t)E * 2;
    int2* st2  = (int2*)(wsi + o); o += (size_t)E * 2;

    int gC = (E + EPB - 1) / EPB;              // 391
    int gW = (N + 3) / 4;                      // 25000

    k_zero<<<1, 1024, 0, stream>>>(gcnt, NB);
    k_count<<<gC, CTH, 0, stream>>>(col, gcnt, E, NB);
    k_scan<<<1, 1024, 0, stream>>>(gcnt, bo, bcur, offs, NB, N, E);
    k_part<<<gC, CTH, 0, stream>>>(row, col, ew, bcur, st, E, NB);
    k_sort<<<NB, 256, 0, stream>>>(bo, st, st2, offs, dinv, N);
    k_gemm1<<<(N + 255) / 256, 256, 0, stream>>>(x, W1, dinv, h1b, N);
    k_agg1<<<gW, 256, 0, stream>>>(offs, st2, dinv, h1b, b1, a1b, N);
    k_agg2<<<gW, 256, 0, stream>>>(offs, st2, dinv, a1b, W2, b2, out, N);
}

// Round 3
// 594.214 us; speedup vs baseline: 1.1540x; 1.1540x over previous
//
#include <hip/hip_runtime.h>
#include <hip/hip_bf16.h>
#include <math.h>

#define F_IN 512
#define HID  16
#define C_OUT 40

#define BSH    7            // 128 nodes per coarse bucket
#define BNODES 128
#define MAXNB  1024         // N=100000 -> NB=782

#define EPB 8192            // edges per block in count/partition
#define CTH 512

__device__ __forceinline__ unsigned short f2bf(float f) {
    unsigned u = __float_as_uint(f);
    unsigned r = (u + 0x7FFF + ((u >> 16) & 1)) >> 16;   // RNE
    return (unsigned short)r;
}
__device__ __forceinline__ float bf2f(unsigned short h) {
    return __uint_as_float(((unsigned)h) << 16);
}

// ---------------------------------------------------------------------------
// K0: zero global bucket counters
// ---------------------------------------------------------------------------
__global__ __launch_bounds__(1024) void k_zero(int* __restrict__ g, int n) {
    int t = threadIdx.x;
    if (t < n) g[t] = 0;
}

// ---------------------------------------------------------------------------
// K1: coarse bucket histogram via LDS
// ---------------------------------------------------------------------------
__global__ __launch_bounds__(CTH) void k_count(const int* __restrict__ col,
                                               int* __restrict__ gcnt,
                                               int E, int NB) {
    __shared__ int lc[MAXNB];
    int t = threadIdx.x;
    for (int i = t; i < NB; i += CTH) lc[i] = 0;
    __syncthreads();
    int base = blockIdx.x * EPB;
#pragma unroll
    for (int i = 0; i < EPB / CTH; ++i) {
        int e = base + t + i * CTH;
        if (e < E) atomicAdd(&lc[col[e] >> BSH], 1);
    }
    __syncthreads();
    for (int i = t; i < NB; i += CTH)
        if (lc[i]) atomicAdd(&gcnt[i], lc[i]);
}

// ---------------------------------------------------------------------------
// K2: exclusive scan of bucket counts; also offs[N] = E sentinel
// ---------------------------------------------------------------------------
__global__ __launch_bounds__(1024) void k_scan(const int* __restrict__ gcnt,
                                               int* __restrict__ bo,
                                               int* __restrict__ bcur,
                                               int* __restrict__ offs,
                                               int NB, int N, int E) {
    __shared__ int s[1024];
    int t = threadIdx.x;
    int v = (t < NB) ? gcnt[t] : 0;
    s[t] = v;
    __syncthreads();
    for (int off = 1; off < 1024; off <<= 1) {
        int x = (t >= off) ? s[t - off] : 0;
        __syncthreads();
        s[t] += x;
        __syncthreads();
    }
    if (t < NB) { int o = s[t] - v; bo[t] = o; bcur[t] = o; }
    if (t == 0) { bo[NB] = E; offs[N] = E; }
}

// ---------------------------------------------------------------------------
// K3: partition edges into coarse buckets. record .x=(row<<7)|col_low, .y=ew
// ---------------------------------------------------------------------------
__global__ __launch_bounds__(CTH) void k_part(const int* __restrict__ row,
                                              const int* __restrict__ col,
                                              const float* __restrict__ ew,
                                              int* __restrict__ bcur,
                                              int2* __restrict__ st,
                                              int E, int NB) {
    __shared__ int lc[MAXNB];
    __shared__ int lb[MAXNB];
    int t = threadIdx.x;
    for (int i = t; i < NB; i += CTH) lc[i] = 0;
    __syncthreads();
    int base = blockIdx.x * EPB;
#pragma unroll
    for (int i = 0; i < EPB / CTH; ++i) {
        int e = base + t + i * CTH;
        if (e < E) atomicAdd(&lc[col[e] >> BSH], 1);
    }
    __syncthreads();
    for (int i = t; i < NB; i += CTH) {
        int c = lc[i];
        lb[i] = c ? atomicAdd(&bcur[i], c) : 0;
    }
    __syncthreads();
    for (int i = t; i < NB; i += CTH) lc[i] = 0;  // reuse as rank counter
    __syncthreads();
#pragma unroll
    for (int i = 0; i < EPB / CTH; ++i) {
        int e = base + t + i * CTH;
        if (e < E) {
            int c = col[e];
            int b = c >> BSH;
            int r = atomicAdd(&lc[b], 1);
            st[lb[b] + r] = make_int2((row[e] << BSH) | (c & (BNODES - 1)),
                                      __float_as_int(ew[e]));
        }
    }
}

// ---------------------------------------------------------------------------
// K4: per-bucket exact counting sort (two passes, no record buffer in LDS).
// ---------------------------------------------------------------------------
__global__ __launch_bounds__(256) void k_sort(const int* __restrict__ bo,
                                              const int2* __restrict__ st,
                                              int2* __restrict__ st2,
                                              int* __restrict__ offs,
                                              float* __restrict__ dinv, int N) {
    __shared__ int cnt[BNODES];
    __shared__ float wsum[BNODES];
    __shared__ int off[BNODES];
    int t = threadIdx.x;
    int b = blockIdx.x;
    if (t < BNODES) { cnt[t] = 0; wsum[t] = 0.0f; }
    __syncthreads();
    int beg = bo[b], end = bo[b + 1];
    // pass A: histogram + weighted degree
    for (int e = beg + t; e < end; e += 256) {
        int2 rec = st[e];
        int cl = rec.x & (BNODES - 1);
        atomicAdd(&cnt[cl], 1);
        atomicAdd(&wsum[cl], __int_as_float(rec.y));
    }
    __syncthreads();
    // scan cnt[128] (Hillis-Steele)
    if (t < BNODES) off[t] = cnt[t];
    __syncthreads();
    for (int o = 1; o < BNODES; o <<= 1) {
        int v = (t < BNODES && t >= o) ? off[t - o] : 0;
        __syncthreads();
        if (t < BNODES) off[t] += v;
        __syncthreads();
    }
    if (t < BNODES) {
        int ex = off[t] - cnt[t];       // exclusive
        off[t] = ex;
        int n = b * BNODES + t;
        if (n < N) {
            offs[n] = beg + ex;
            dinv[n] = rsqrtf(1.0f + wsum[t]);
        }
        cnt[t] = 0;                     // reuse as rank counter
    }
    __syncthreads();
    // pass B: place
    for (int e = beg + t; e < end; e += 256) {
        int2 rec = st[e];
        int cl = rec.x & (BNODES - 1);
        int r = atomicAdd(&cnt[cl], 1);
        st2[beg + off[cl] + r] = make_int2(rec.x >> BSH, rec.y);
    }
}

// ---------------------------------------------------------------------------
// K5: h1' = dinv * (x @ W1), stored bf16 (16 x bf16 = 32 B per node).
// Wave-per-row-group, lane-per-k-slice: lane i permanently owns k = 4i..4i+3
// (and 256+4i..) with its W fragment preloaded in 128 VGPRs. Per row the wave
// issues two fully-contiguous 1 KB loads (8 cache lines each -- fixes the
// 64-line-per-instruction scatter of thread-per-row, which capped BW at
// ~850 GB/s), does 128 static-indexed FMAs, then a j-splitting butterfly
// reduce; lane ends holding j = bitrev4(lane&15).
// ---------------------------------------------------------------------------
#define ROWS_PER_WAVE 16

__global__ __launch_bounds__(256, 1) void k_gemm1(const float* __restrict__ x,
                                                  const float* __restrict__ W,
                                                  const float* __restrict__ dinv,
                                                  unsigned short* __restrict__ hb,
                                                  int N) {
    const int t = threadIdx.x;
    const int lane = t & 63;
    const int wv = blockIdx.x * 4 + (t >> 6);
    const int r0 = wv * ROWS_PER_WAVE;
    if (r0 >= N) return;
    const int rend = (r0 + ROWS_PER_WAVE < N) ? r0 + ROWS_PER_WAVE : N;

    // one-time W fragment preload (L2-hot, 32 KB shared by all waves)
    float4 Wa[4][4], Wb[4][4];   // [q = k-sub][j4], k = 4*lane+q / 256+4*lane+q
    const float4* W4 = (const float4*)W;   // float4 idx = k*4 + j4
#pragma unroll
    for (int q = 0; q < 4; ++q)
#pragma unroll
        for (int j4 = 0; j4 < 4; ++j4) {
            Wa[q][j4] = W4[(4 * lane + q) * 4 + j4];
            Wb[q][j4] = W4[(256 + 4 * lane + q) * 4 + j4];
        }

    const float4* xb4 = (const float4*)x;  // row r: float4s [r*128, r*128+128)
    // prefetch first row
    float4 pa = xb4[(size_t)r0 * 128 + lane];
    float4 pb = xb4[(size_t)r0 * 128 + 64 + lane];

    for (int r = r0; r < rend; ++r) {
        float4 ca = pa, cb = pb;
        if (r + 1 < rend) {
            pa = xb4[(size_t)(r + 1) * 128 + lane];
            pb = xb4[(size_t)(r + 1) * 128 + 64 + lane];
        }
        float acc[16];
#pragma unroll
        for (int j = 0; j < 16; ++j) acc[j] = 0.0f;
        const float xs0[4] = {ca.x, ca.y, ca.z, ca.w};
        const float xs1[4] = {cb.x, cb.y, cb.z, cb.w};
#pragma unroll
        for (int q = 0; q < 4; ++q) {
#pragma unroll
            for (int j4 = 0; j4 < 4; ++j4) {
                acc[j4 * 4 + 0] += xs0[q] * Wa[q][j4].x;
                acc[j4 * 4 + 1] += xs0[q] * Wa[q][j4].y;
                acc[j4 * 4 + 2] += xs0[q] * Wa[q][j4].z;
                acc[j4 * 4 + 3] += xs0[q] * Wa[q][j4].w;
            }
        }
#pragma unroll
        for (int q = 0; q < 4; ++q) {
#pragma unroll
            for (int j4 = 0; j4 < 4; ++j4) {
                acc[j4 * 4 + 0] += xs1[q] * Wb[q][j4].x;
                acc[j4 * 4 + 1] += xs1[q] * Wb[q][j4].y;
                acc[j4 * 4 + 2] += xs1[q] * Wb[q][j4].z;
                acc[j4 * 4 + 3] += xs1[q] * Wb[q][j4].w;
            }
        }

        // j-splitting butterfly: each round lanes exchange half their j's.
        // After round k, lane holds j-set determined by its low k bits.
        const int b0 = lane & 1;
        float v8[8];
#pragma unroll
        for (int m = 0; m < 8; ++m) {
            float lo = acc[m], hi = acc[m + 8];
            float sent = b0 ? lo : hi;
            float recv = __shfl_xor(sent, 1, 64);
            float keep = b0 ? hi : lo;
            v8[m] = keep + recv;
        }
        const int b1 = (lane >> 1) & 1;
        float v4[4];
#pragma unroll
        for (int m = 0; m < 4; ++m) {
            float lo = v8[m], hi = v8[m + 4];
            float sent = b1 ? lo : hi;
            float recv = __shfl_xor(sent, 2, 64);
            float keep = b1 ? hi : lo;
            v4[m] = keep + recv;
        }
        const int b2 = (lane >> 2) & 1;
        float v2[2];
#pragma unroll
        for (int m = 0; m < 2; ++m) {
            float lo = v4[m], hi = v4[m + 2];
            float sent = b2 ? lo : hi;
            float recv = __shfl_xor(sent, 4, 64);
            float keep = b2 ? hi : lo;
            v2[m] = keep + recv;
        }
        const int b3 = (lane >> 3) & 1;
        float v1;
        {
            float lo = v2[0], hi = v2[1];
            float sent = b3 ? lo : hi;
            float recv = __shfl_xor(sent, 8, 64);
            float keep = b3 ? hi : lo;
            v1 = keep + recv;
        }
        v1 += __shfl_xor(v1, 16, 64);
        v1 += __shfl_xor(v1, 32, 64);

        float d = dinv[r];                       // wave-uniform -> s_load
        if (lane < 16) {
            int j = ((lane & 1) << 3) | (((lane >> 1) & 1) << 2) |
                    (((lane >> 2) & 1) << 1) | ((lane >> 3) & 1);
            hb[(size_t)r * HID + j] = f2bf(d * v1);
        }
    }
}

// ---------------------------------------------------------------------------
// K6: layer-1 aggregate. Wave per node; lane = 4*i+q (i edge slot, q dim quad).
// ---------------------------------------------------------------------------
__global__ __launch_bounds__(256) void k_agg1(const int* __restrict__ offs,
                                              const int2* __restrict__ st2,
                                              const float* __restrict__ dinv,
                                              const unsigned short* __restrict__ srcb,
                                              const float* __restrict__ bias,
                                              unsigned short* __restrict__ dstb,
                                              int N) {
    int t = threadIdx.x;
    int lane = t & 63, w = t >> 6;
    int n = blockIdx.x * 4 + w;
    if (n >= N) return;
    int q = lane & 3, i = lane >> 2;
    int beg = offs[n], end = offs[n + 1];
    float4 acc = make_float4(0.f, 0.f, 0.f, 0.f);
    for (int e = beg + i; e < end; e += 16) {
        int2 rec = st2[e];
        float wt = __int_as_float(rec.y);
        ushort4 v = ((const ushort4*)(srcb + (size_t)rec.x * HID))[q];
        acc.x += wt * bf2f(v.x);
        acc.y += wt * bf2f(v.y);
        acc.z += wt * bf2f(v.z);
        acc.w += wt * bf2f(v.w);
    }
#pragma unroll
    for (int off = 4; off < 64; off <<= 1) {
        acc.x += __shfl_xor(acc.x, off, 64);
        acc.y += __shfl_xor(acc.y, off, 64);
        acc.z += __shfl_xor(acc.z, off, 64);
        acc.w += __shfl_xor(acc.w, off, 64);
    }
    if (i == 0) {
        float d = dinv[n];
        ushort4 sv = ((const ushort4*)(srcb + (size_t)n * HID))[q];
        float4 bq = ((const float4*)bias)[q];
        float r0 = d * fmaxf(d * (acc.x + bf2f(sv.x)) + bq.x, 0.f);
        float r1 = d * fmaxf(d * (acc.y + bf2f(sv.y)) + bq.y, 0.f);
        float r2 = d * fmaxf(d * (acc.z + bf2f(sv.z)) + bq.z, 0.f);
        float r3 = d * fmaxf(d * (acc.w + bf2f(sv.w)) + bq.w, 0.f);
        ((ushort4*)(dstb + (size_t)n * HID))[q] =
            make_ushort4(f2bf(r0), f2bf(r1), f2bf(r2), f2bf(r3));
    }
}

// ---------------------------------------------------------------------------
// K7: layer-2 aggregate fused with W2 matvec + bias + log_softmax.
// ---------------------------------------------------------------------------
__global__ __launch_bounds__(256) void k_agg2(const int* __restrict__ offs,
                                              const int2* __restrict__ st2,
                                              const float* __restrict__ dinv,
                                              const unsigned short* __restrict__ srcb,
                                              const float* __restrict__ W2,
                                              const float* __restrict__ b2,
                                              float* __restrict__ out, int N) {
    __shared__ float Ws[HID * C_OUT];
    __shared__ float bs[C_OUT];
    int t = threadIdx.x;
    for (int iw = t; iw < HID * C_OUT; iw += 256) Ws[iw] = W2[iw];
    if (t < C_OUT) bs[t] = b2[t];
    __syncthreads();

    int lane = t & 63, w = t >> 6;
    int n = blockIdx.x * 4 + w;
    if (n >= N) return;
    int q = lane & 3, i = lane >> 2;
    int beg = offs[n], end = offs[n + 1];
    float4 acc = make_float4(0.f, 0.f, 0.f, 0.f);
    for (int e = beg + i; e < end; e += 16) {
        int2 rec = st2[e];
        float wt = __int_as_float(rec.y);
        ushort4 v = ((const ushort4*)(srcb + (size_t)rec.x * HID))[q];
        acc.x += wt * bf2f(v.x);
        acc.y += wt * bf2f(v.y);
        acc.z += wt * bf2f(v.z);
        acc.w += wt * bf2f(v.w);
    }
#pragma unroll
    for (int off = 4; off < 64; off <<= 1) {
        acc.x += __shfl_xor(acc.x, off, 64);
        acc.y += __shfl_xor(acc.y, off, 64);
        acc.z += __shfl_xor(acc.z, off, 64);
        acc.w += __shfl_xor(acc.w, off, 64);
    }
    // every lane now holds the full sum for its quad q
    float d = dinv[n];
    ushort4 sv = ((const ushort4*)(srcb + (size_t)n * HID))[q];
    float gq[4];
    gq[0] = d * (acc.x + bf2f(sv.x));
    gq[1] = d * (acc.y + bf2f(sv.y));
    gq[2] = d * (acc.z + bf2f(sv.z));
    gq[3] = d * (acc.w + bf2f(sv.w));
    // assemble all 16 dims in every lane (quads live in lanes base..base+3)
    float g16[16];
    int base = lane & ~3;
#pragma unroll
    for (int qq = 0; qq < 4; ++qq) {
#pragma unroll
        for (int k = 0; k < 4; ++k)
            g16[qq * 4 + k] = __shfl(gq[k], base + qq, 64);
    }
    float logit = -INFINITY;
    if (lane < C_OUT) {
        float a = bs[lane];
#pragma unroll
        for (int j = 0; j < HID; ++j) a += g16[j] * Ws[j * C_OUT + lane];
        logit = a;
    }
    float m = logit;
#pragma unroll
    for (int off = 32; off > 0; off >>= 1) m = fmaxf(m, __shfl_xor(m, off, 64));
    float ex = (lane < C_OUT) ? __expf(logit - m) : 0.0f;
    float s = ex;
#pragma unroll
    for (int off = 32; off > 0; off >>= 1) s += __shfl_xor(s, off, 64);
    if (lane < C_OUT) out[(size_t)n * C_OUT + lane] = logit - m - __logf(s);
}

// ---------------------------------------------------------------------------
extern "C" void kernel_launch(void* const* d_in, const int* in_sizes, int n_in,
                              void* d_out, int out_size, void* d_ws, size_t ws_size,
                              hipStream_t stream) {
    const float* x   = (const float*)d_in[0];
    const int*   ei  = (const int*)d_in[1];
    const float* ew  = (const float*)d_in[2];
    const float* W1  = (const float*)d_in[3];
    const float* b1  = (const float*)d_in[4];
    const float* W2  = (const float*)d_in[5];
    const float* b2  = (const float*)d_in[6];
    float* out = (float*)d_out;

    const int N = in_sizes[0] / F_IN;          // 100000
    const int E = in_sizes[2];                 // 3200000
    const int* row = ei;
    const int* col = ei + E;
    const int NB = (N + BNODES - 1) >> BSH;    // 782

    // workspace carve (4-byte words)
    int* wsi = (int*)d_ws;
    size_t o = 0;
    int* gcnt  = wsi + o; o += MAXNB;
    int* bo    = wsi + o; o += MAXNB + 1;
    int* bcur  = wsi + o; o += MAXNB;
    int* offs  = wsi + o; o += (size_t)N + 8;
    float* dinv = (float*)(wsi + o); o += N;
    unsigned short* h1b = (unsigned short*)(wsi + o); o += (size_t)N * HID / 2;
    unsigned short* a1b = (unsigned short*)(wsi + o); o += (size_t)N * HID / 2;
    int2* st   = (int2*)(wsi + o); o += (size_t)E * 2;
    int2* st2  = (int2*)(wsi + o); o += (size_t)E * 2;

    int gC = (E + EPB - 1) / EPB;              // 391
    int gW = (N + 3) / 4;                      // 25000
    int gG = (N + 4 * ROWS_PER_WAVE - 1) / (4 * ROWS_PER_WAVE);   // 1563

    k_zero<<<1, 1024, 0, stream>>>(gcnt, NB);
    k_count<<<gC, CTH, 0, stream>>>(col, gcnt, E, NB);
    k_scan<<<1, 1024, 0, stream>>>(gcnt, bo, bcur, offs, NB, N, E);
    k_part<<<gC, CTH, 0, stream>>>(row, col, ew, bcur, st, E, NB);
    k_sort<<<NB, 256, 0, stream>>>(bo, st, st2, offs, dinv, N);
    k_gemm1<<<gG, 256, 0, stream>>>(x, W1, dinv, h1b, N);
    k_agg1<<<gW, 256, 0, stream>>>(offs, st2, dinv, h1b, b1, a1b, N);
    k_agg2<<<gW, 256, 0, stream>>>(offs, st2, dinv, a1b, W2, b2, out, N);
}